// Round 4
// baseline (3902.000 us; speedup 1.0000x reference)
//
#include <hip/hip_runtime.h>
#include <hip/hip_bf16.h>
#include <math.h>

#define NTOK   4096   // B*T
#define TSEQ   2048
#define DMODEL 1024
#define DINNER 2048
#define NSTATE 16
#define DTRANK 64
#define NEXP   8
#define DFF    2048

__device__ __forceinline__ float siluf(float x){ return x / (1.f + expf(-x)); }

// ---------------------------------------------------------------------------
// zero counters (cnt/fill/off = 64 ints)
// ---------------------------------------------------------------------------
__global__ void zero_kernel(int* __restrict__ p){ p[threadIdx.x] = 0; }

// ---------------------------------------------------------------------------
// Tiled fp32 GEMM: C[M,N] = A[M,K] @ W[N,K]^T (+epilogue)
// 64x64 tile, 256 threads, 4x4 per thread, K-major LDS, float4 global loads.
// EPI: 0 = +bias | 1 = plain | 2 = +bias,softplus | 3 = +resid
// ---------------------------------------------------------------------------
template<int EPI>
__global__ __launch_bounds__(256) void gemm_tn(
    const float* __restrict__ A, int lda,
    const float* __restrict__ W, int ldw,
    int M, int N, int K,
    const float* __restrict__ bias,
    const float* __restrict__ resid, int ldr,
    float* __restrict__ out, int ldo)
{
  const int tid = threadIdx.x;
  const int m0 = blockIdx.y * 64;
  const int n0 = blockIdx.x * 64;
  const int tx = tid & 15, ty = tid >> 4;
  const int lr = tid >> 2;          // row handled by this thread in loads
  const int lk = (tid & 3) * 4;     // k base within 16-wide k tile

  __shared__ __align__(16) float As[16][68];
  __shared__ __align__(16) float Ws[16][68];

  float acc[4][4];
  #pragma unroll
  for (int i=0;i<4;i++)
    #pragma unroll
    for (int j=0;j<4;j++) acc[i][j]=0.f;

  const int gm = m0 + lr;
  const int gn = n0 + lr;
  const bool am = (gm < M);
  const bool wn = (gn < N);
  const float* Arow = A + (size_t)gm*lda;
  const float* Wrow = W + (size_t)gn*ldw;

  for (int kt = 0; kt < K; kt += 16){
    float4 a4 = am ? *(const float4*)(Arow + kt + lk) : make_float4(0,0,0,0);
    float4 w4 = wn ? *(const float4*)(Wrow + kt + lk) : make_float4(0,0,0,0);
    As[lk+0][lr]=a4.x; As[lk+1][lr]=a4.y; As[lk+2][lr]=a4.z; As[lk+3][lr]=a4.w;
    Ws[lk+0][lr]=w4.x; Ws[lk+1][lr]=w4.y; Ws[lk+2][lr]=w4.z; Ws[lk+3][lr]=w4.w;
    __syncthreads();
    #pragma unroll
    for (int k=0;k<16;k++){
      float4 av = *(const float4*)&As[k][ty*4];
      float4 bv = *(const float4*)&Ws[k][tx*4];
      float a[4] = {av.x, av.y, av.z, av.w};
      float b[4] = {bv.x, bv.y, bv.z, bv.w};
      #pragma unroll
      for (int i=0;i<4;i++)
        #pragma unroll
        for (int j=0;j<4;j++)
          acc[i][j] = fmaf(a[i], b[j], acc[i][j]);
    }
    __syncthreads();
  }

  #pragma unroll
  for (int i=0;i<4;i++){
    int om = m0 + ty*4 + i;
    if (om >= M) continue;
    #pragma unroll
    for (int j=0;j<4;j++){
      int on = n0 + tx*4 + j;
      if (on >= N) continue;
      float v = acc[i][j];
      if (EPI == 0){ v += bias[on]; }
      else if (EPI == 2){ v += bias[on]; v = (v > 20.f) ? v : log1pf(expf(v)); }
      else if (EPI == 3){ v += resid[(size_t)om*ldr+on]; }
      out[(size_t)om*ldo+on] = v;
    }
  }
}

// ---------------------------------------------------------------------------
// LayerNorm over D=1024, one token per 256-thread block (all fp32)
// ---------------------------------------------------------------------------
__global__ __launch_bounds__(256) void ln_kernel(
    const float* __restrict__ x, const float* __restrict__ g, const float* __restrict__ b,
    float* __restrict__ out)
{
  int tok = blockIdx.x;
  int tid = threadIdx.x;
  const float* row = x + (size_t)tok * DMODEL;
  float v[4];
  float s = 0.f, sq = 0.f;
  #pragma unroll
  for (int j=0;j<4;j++){
    v[j] = row[j*256 + tid];
    s += v[j]; sq += v[j]*v[j];
  }
  #pragma unroll
  for (int o=1;o<64;o<<=1){ s += __shfl_xor(s,o,64); sq += __shfl_xor(sq,o,64); }
  __shared__ float ss[4], ssq[4];
  int wid = tid >> 6, lane = tid & 63;
  if (lane == 0){ ss[wid]=s; ssq[wid]=sq; }
  __syncthreads();
  s  = ss[0]+ss[1]+ss[2]+ss[3];
  sq = ssq[0]+ssq[1]+ssq[2]+ssq[3];
  float mu = s * (1.f/DMODEL);
  float var = sq * (1.f/DMODEL) - mu*mu;
  float rs = rsqrtf(var + 1e-5f);
  #pragma unroll
  for (int j=0;j<4;j++){
    int d = j*256 + tid;
    out[(size_t)tok*DMODEL + d] = (v[j]-mu)*rs*g[d] + b[d];
  }
}

// ---------------------------------------------------------------------------
// Causal depthwise conv (KC=4) + SiLU.  xi = xz[:, 0:2048] (row stride 4096)
// ---------------------------------------------------------------------------
__global__ __launch_bounds__(256) void conv_kernel(
    const float* __restrict__ xz, const float* __restrict__ cw,
    const float* __restrict__ cb, float* __restrict__ xc)
{
  int i = blockIdx.x*256 + threadIdx.x;      // < NTOK*DINNER
  int tok = i >> 11;
  int ch  = i & 2047;
  int t   = tok & (TSEQ-1);
  int b   = tok >> 11;
  float acc = cb[ch];
  #pragma unroll
  for (int k=0;k<4;k++){
    int tt = t + k - 3;
    if (tt >= 0)
      acc = fmaf(cw[ch*4 + k], xz[(size_t)((b<<11)+tt)*4096 + ch], acc);
  }
  xc[i] = siluf(acc);
}

// ---------------------------------------------------------------------------
// Fused selective scan + skip + gate: thread per (b,ch,n); 16 lanes per channel.
// dt lives in the xi half of xz (stride 4096); z in the z half.
// y = (scan_y + xc*D_skip) * silu(z), written IN-PLACE into xc (wave lockstep:
// all 16 lanes read xc[tok,ch] before lane 0's write).
// ---------------------------------------------------------------------------
__global__ __launch_bounds__(256) void scan_kernel(
    const float* __restrict__ xz, float* __restrict__ xc,
    const float* __restrict__ proj, const float* __restrict__ A_log,
    const float* __restrict__ Dskip)
{
  int tid = threadIdx.x;
  int gc = blockIdx.x*16 + (tid >> 4);   // 0..4095 = b*2048+ch
  int n  = tid & 15;
  int b  = gc >> 11;
  int ch = gc & 2047;
  float A  = -expf(A_log[ch*NSTATE + n]);
  float Dv = Dskip[ch];
  float h = 0.f;
  for (int t=0; t<TSEQ; t++){
    int tok = (b<<11) + t;
    float dtv = xz[(size_t)tok*4096 + ch];
    float xt  = xc[(size_t)tok*2048 + ch];
    float Bn  = proj[(size_t)tok*96 + 64 + n];
    float Cn  = proj[(size_t)tok*96 + 80 + n];
    h = expf(dtv*A)*h + dtv*xt*Bn;
    float p = h*Cn;
    p += __shfl_xor(p,1,64);
    p += __shfl_xor(p,2,64);
    p += __shfl_xor(p,4,64);
    p += __shfl_xor(p,8,64);
    if (n == 0){
      float zv = xz[(size_t)tok*4096 + 2048 + ch];
      xc[(size_t)tok*2048 + ch] = (p + xt*Dv) * siluf(zv);
    }
  }
}

// ---------------------------------------------------------------------------
// Router: logits, softmax (-> d_out probs), top-2, atomic expert counts
// ---------------------------------------------------------------------------
__global__ __launch_bounds__(256) void router_kernel(
    const float* __restrict__ hmoe, const float* __restrict__ rw,
    float* __restrict__ probs_out, int* __restrict__ cnt,
    int* __restrict__ tok_e0, int* __restrict__ tok_e1,
    float* __restrict__ tok_w0, float* __restrict__ tok_w1)
{
  int tok = blockIdx.x;
  int tid = threadIdx.x;
  int e = tid >> 5, l = tid & 31;
  float s = 0.f;
  const float* row = hmoe + (size_t)tok*DMODEL;
  const float* wr  = rw + (size_t)e*DMODEL;
  for (int d=l; d<DMODEL; d+=32) s = fmaf(row[d], wr[d], s);
  #pragma unroll
  for (int o=1;o<32;o<<=1) s += __shfl_xor(s,o,64);
  __shared__ float lg[8];
  if (l==0) lg[e]=s;
  __syncthreads();
  if (tid==0){
    float mx = lg[0];
    for (int k=1;k<8;k++) mx = fmaxf(mx, lg[k]);
    float pe[8]; float den=0.f;
    for (int k=0;k<8;k++){ pe[k]=expf(lg[k]-mx); den+=pe[k]; }
    float inv = 1.f/den;
    for (int k=0;k<8;k++) probs_out[tok*8+k] = pe[k]*inv;
    int i0=0;
    for (int k=1;k<8;k++) if (pe[k] > pe[i0]) i0=k;
    int i1 = (i0==0)?1:0;
    for (int k=0;k<8;k++) if (k!=i0 && pe[k] > pe[i1]) i1=k;
    float v0=pe[i0], v1=pe[i1], sw=v0+v1;
    tok_e0[tok]=i0; tok_e1[tok]=i1;
    tok_w0[tok]=v0/sw; tok_w1[tok]=v1/sw;
    atomicAdd(&cnt[i0],1); atomicAdd(&cnt[i1],1);
  }
}

__global__ void prefix_kernel(const int* cnt, int* off, int* fill){
  if (threadIdx.x==0){
    int s=0;
    for (int e=0;e<NEXP;e++){ off[e]=s; s+=cnt[e]; fill[e]=0; }
  }
}

__global__ __launch_bounds__(256) void fill_kernel(
    const int* tok_e0, const int* tok_e1, const float* tok_w0, const float* tok_w1,
    const int* off, int* fill, int* slot_tok, float* slot_w)
{
  int tok = blockIdx.x*256 + threadIdx.x;
  int e0=tok_e0[tok], e1=tok_e1[tok];
  int p0 = atomicAdd(&fill[e0],1); int s0 = off[e0]+p0;
  slot_tok[s0]=tok; slot_w[s0]=tok_w0[tok];
  int p1 = atomicAdd(&fill[e1],1); int s1 = off[e1]+p1;
  slot_tok[s1]=tok; slot_w[s1]=tok_w1[tok];
}

// ---------------------------------------------------------------------------
// MoE expert-gathered GEMM1: H1[slot,DFF] = silu(hmoe[tok] @ w1[e]^T + b1[e])
// ---------------------------------------------------------------------------
__global__ __launch_bounds__(256) void moe_gemm1(
    const float* __restrict__ hmoe, const float* __restrict__ w1, const float* __restrict__ b1,
    const int* __restrict__ cnt, const int* __restrict__ off,
    const int* __restrict__ slot_tok, float* __restrict__ H1)
{
  int e = blockIdx.z;
  int c = cnt[e];
  int r0 = blockIdx.y*64;
  if (r0 >= c) return;
  int base = off[e];
  int tid = threadIdx.x;
  __shared__ int toks[64];
  if (tid < 64) toks[tid] = (r0 + tid < c) ? slot_tok[base + r0 + tid] : -1;
  __syncthreads();

  const float* W = w1 + (size_t)e*DFF*DMODEL;
  int n0 = blockIdx.x*64;
  int tx = tid & 15, ty = tid >> 4;
  int lr = tid >> 2, lk = (tid & 3)*4;
  __shared__ __align__(16) float As[16][68];
  __shared__ __align__(16) float Ws[16][68];
  float acc[4][4];
  #pragma unroll
  for (int i=0;i<4;i++)
    #pragma unroll
    for (int j=0;j<4;j++) acc[i][j]=0.f;

  int tA = toks[lr];
  const float* Arow = hmoe + (size_t)tA*DMODEL;
  const float* Wrow = W + (size_t)(n0+lr)*DMODEL;
  for (int kt=0; kt<DMODEL; kt+=16){
    float4 a4 = (tA>=0) ? *(const float4*)(Arow + kt + lk) : make_float4(0,0,0,0);
    float4 w4 = *(const float4*)(Wrow + kt + lk);
    As[lk+0][lr]=a4.x; As[lk+1][lr]=a4.y; As[lk+2][lr]=a4.z; As[lk+3][lr]=a4.w;
    Ws[lk+0][lr]=w4.x; Ws[lk+1][lr]=w4.y; Ws[lk+2][lr]=w4.z; Ws[lk+3][lr]=w4.w;
    __syncthreads();
    #pragma unroll
    for (int k=0;k<16;k++){
      float4 av = *(const float4*)&As[k][ty*4];
      float4 bv = *(const float4*)&Ws[k][tx*4];
      float a[4] = {av.x, av.y, av.z, av.w};
      float b[4] = {bv.x, bv.y, bv.z, bv.w};
      #pragma unroll
      for (int i=0;i<4;i++)
        #pragma unroll
        for (int j=0;j<4;j++)
          acc[i][j] = fmaf(a[i], b[j], acc[i][j]);
    }
    __syncthreads();
  }
  #pragma unroll
  for (int i=0;i<4;i++){
    int r = ty*4 + i;
    if (toks[r] < 0) continue;
    #pragma unroll
    for (int j=0;j<4;j++){
      int gn = n0 + tx*4 + j;
      float v = acc[i][j] + b1[(size_t)e*DFF + gn];
      H1[(size_t)(base + r0 + r)*DFF + gn] = siluf(v);
    }
  }
}

// ---------------------------------------------------------------------------
// MoE GEMM2: hres[tok] += w_slot * (H1[slot] @ w2[e]^T + b2[e])   (atomic)
// ---------------------------------------------------------------------------
__global__ __launch_bounds__(256) void moe_gemm2(
    const float* __restrict__ H1, const float* __restrict__ w2, const float* __restrict__ b2,
    const int* __restrict__ cnt, const int* __restrict__ off,
    const int* __restrict__ slot_tok, const float* __restrict__ slot_w,
    float* __restrict__ hres)
{
  int e = blockIdx.z;
  int c = cnt[e];
  int r0 = blockIdx.y*64;
  if (r0 >= c) return;
  int base = off[e];
  int tid = threadIdx.x;
  __shared__ int toks[64];
  __shared__ float wts[64];
  if (tid < 64){
    int r = r0 + tid;
    toks[tid] = (r<c) ? slot_tok[base+r] : -1;
    wts[tid]  = (r<c) ? slot_w[base+r] : 0.f;
  }
  __syncthreads();

  const float* W = w2 + (size_t)e*DMODEL*DFF;
  int n0 = blockIdx.x*64;
  int tx = tid & 15, ty = tid >> 4;
  int lr = tid >> 2, lk = (tid & 3)*4;
  bool av_ok = (toks[lr] >= 0);
  __shared__ __align__(16) float As[16][68];
  __shared__ __align__(16) float Ws[16][68];
  float acc[4][4];
  #pragma unroll
  for (int i=0;i<4;i++)
    #pragma unroll
    for (int j=0;j<4;j++) acc[i][j]=0.f;

  const float* Arow = H1 + (size_t)(base + r0 + lr)*DFF;
  const float* Wrow = W + (size_t)(n0+lr)*DFF;
  for (int kt=0; kt<DFF; kt+=16){
    float4 a4 = av_ok ? *(const float4*)(Arow + kt + lk) : make_float4(0,0,0,0);
    float4 w4 = *(const float4*)(Wrow + kt + lk);
    As[lk+0][lr]=a4.x; As[lk+1][lr]=a4.y; As[lk+2][lr]=a4.z; As[lk+3][lr]=a4.w;
    Ws[lk+0][lr]=w4.x; Ws[lk+1][lr]=w4.y; Ws[lk+2][lr]=w4.z; Ws[lk+3][lr]=w4.w;
    __syncthreads();
    #pragma unroll
    for (int k=0;k<16;k++){
      float4 av = *(const float4*)&As[k][ty*4];
      float4 bv = *(const float4*)&Ws[k][tx*4];
      float a[4] = {av.x, av.y, av.z, av.w};
      float b[4] = {bv.x, bv.y, bv.z, bv.w};
      #pragma unroll
      for (int i=0;i<4;i++)
        #pragma unroll
        for (int j=0;j<4;j++)
          acc[i][j] = fmaf(a[i], b[j], acc[i][j]);
    }
    __syncthreads();
  }
  #pragma unroll
  for (int i=0;i<4;i++){
    int t = toks[ty*4+i];
    if (t < 0) continue;
    float w = wts[ty*4+i];
    #pragma unroll
    for (int j=0;j<4;j++){
      int gn = n0 + tx*4 + j;
      float v = acc[i][j] + b2[(size_t)e*DMODEL + gn];
      atomicAdd(&hres[(size_t)t*DMODEL + gn], w*v);
    }
  }
}

__global__ __launch_bounds__(256) void final_kernel(const float* __restrict__ hres,
                                                    float* __restrict__ out)
{
  int i = blockIdx.x*256 + threadIdx.x;
  out[i] = hres[i];
}

// ---------------------------------------------------------------------------
extern "C" void kernel_launch(void* const* d_in, const int* in_sizes, int n_in,
                              void* d_out, int out_size, void* d_ws, size_t ws_size,
                              hipStream_t stream)
{
  const float* x         = (const float*)d_in[0];
  const float* ln_m_g    = (const float*)d_in[1];
  const float* ln_m_b    = (const float*)d_in[2];
  const float* ln_e_g    = (const float*)d_in[3];
  const float* ln_e_b    = (const float*)d_in[4];
  const float* in_proj_w = (const float*)d_in[5];
  const float* in_proj_b = (const float*)d_in[6];
  const float* conv_w    = (const float*)d_in[7];
  const float* conv_b    = (const float*)d_in[8];
  const float* x_proj_w  = (const float*)d_in[9];
  const float* dt_proj_w = (const float*)d_in[10];
  const float* dt_proj_b = (const float*)d_in[11];
  const float* A_log     = (const float*)d_in[12];
  const float* D_skip    = (const float*)d_in[13];
  const float* out_proj_w= (const float*)d_in[14];
  const float* router_w  = (const float*)d_in[15];
  const float* w1        = (const float*)d_in[16];
  const float* b1        = (const float*)d_in[17];
  const float* w2        = (const float*)d_in[18];
  const float* b2        = (const float*)d_in[19];

  // Workspace (all fp32), peak ~97.6 MB with overlays:
  //   [0,64M)       xz [4096,4096]; xi half reused for dt; after scan dead ->
  //                 hres [4096,1024] at [0,16M), H1 [8192,2048] at [16M,80M)
  //   [64M,96M)     xc [4096,2048] -> y in-place -> tail of H1 overlay
  //   [96M,97.5M)   proj [4096,96]
  //   [97.5M,...)   misc (counters + buckets, ~132 KB)
  // hn (LN output, [4096,1024] fp32 = 16MB) lives in d_out[0,16M) as scratch:
  // fully consumed by in_proj / moe_gemm1 before final_kernel rewrites it.
  char* ws = (char*)d_ws;
  float* xz   = (float*)(ws + 0);
  float* xc   = (float*)(ws + 67108864ull);
  float* proj = (float*)(ws + 100663296ull);
  char*  misc = ws + 102236160ull;
  float* hres = (float*)(ws + 0);
  float* H1   = (float*)(ws + 16777216ull);
  float* hn   = (float*)d_out;
  int*   cnt      = (int*)(misc);
  int*   fill     = (int*)(misc + 64);
  int*   offp     = (int*)(misc + 128);
  int*   tok_e0   = (int*)(misc + 1024);
  int*   tok_e1   = (int*)(misc + 1024 + 16384);
  float* tok_w0   = (float*)(misc + 1024 + 32768);
  float* tok_w1   = (float*)(misc + 1024 + 49152);
  int*   slot_tok = (int*)(misc + 1024 + 65536);
  float* slot_w   = (float*)(misc + 1024 + 98304);
  float* out_h    = (float*)d_out;
  float* probs_out= (float*)d_out + 4194304;

  zero_kernel<<<1, 64, 0, stream>>>(cnt);

  // ---- Mamba branch ----
  ln_kernel<<<NTOK, 256, 0, stream>>>(x, ln_m_g, ln_m_b, hn);
  gemm_tn<0><<<dim3(64,64), 256, 0, stream>>>(
      hn, DMODEL, in_proj_w, DMODEL, NTOK, 4096, DMODEL,
      in_proj_b, nullptr, 0, xz, 4096);
  conv_kernel<<<NTOK*DINNER/256, 256, 0, stream>>>(xz, conv_w, conv_b, xc);
  gemm_tn<1><<<dim3(2,64), 256, 0, stream>>>(
      xc, DINNER, x_proj_w, DINNER, NTOK, 96, DINNER,
      nullptr, nullptr, 0, proj, 96);
  // dt (softplus) -> dead xi half of xz (ldo = 4096)
  gemm_tn<2><<<dim3(32,64), 256, 0, stream>>>(
      proj, 96, dt_proj_w, DTRANK, NTOK, DINNER, DTRANK,
      dt_proj_b, nullptr, 0, xz, 4096);
  // fused scan + D_skip + silu(z) gate; y in-place into xc
  scan_kernel<<<256, 256, 0, stream>>>(xz, xc, proj, A_log, D_skip);
  // out_proj + residual x -> hres
  gemm_tn<3><<<dim3(16,64), 256, 0, stream>>>(
      xc, DINNER, out_proj_w, DINNER, NTOK, DMODEL, DINNER,
      nullptr, x, DMODEL, hres, DMODEL);

  // ---- MoE branch ----
  ln_kernel<<<NTOK, 256, 0, stream>>>(hres, ln_e_g, ln_e_b, hn);
  router_kernel<<<NTOK, 256, 0, stream>>>(hn, router_w, probs_out, cnt,
                                          tok_e0, tok_e1, tok_w0, tok_w1);
  prefix_kernel<<<1, 64, 0, stream>>>(cnt, offp, fill);
  fill_kernel<<<NTOK/256, 256, 0, stream>>>(tok_e0, tok_e1, tok_w0, tok_w1,
                                            offp, fill, slot_tok, slot_w);
  moe_gemm1<<<dim3(DFF/64, 64, NEXP), 256, 0, stream>>>(
      hn, w1, b1, cnt, offp, slot_tok, H1);
  moe_gemm2<<<dim3(DMODEL/64, 64, NEXP), 256, 0, stream>>>(
      H1, w2, b2, cnt, offp, slot_tok, slot_w, hres);

  final_kernel<<<NTOK*DMODEL/256, 256, 0, stream>>>(hres, out_h);
}

// Round 5
// 2602.101 us; speedup vs baseline: 1.4996x; 1.4996x over previous
//
#include <hip/hip_runtime.h>
#include <hip/hip_bf16.h>
#include <math.h>

#define NTOK   4096   // B*T
#define TSEQ   2048
#define DMODEL 1024
#define DINNER 2048
#define NSTATE 16
#define DTRANK 64
#define NEXP   8
#define DFF    2048
#define NCHUNK 16
#define CLEN   128    // TSEQ / NCHUNK

__device__ __forceinline__ float siluf(float x){ return x / (1.f + expf(-x)); }

// ---------------------------------------------------------------------------
// zero counters (cnt/fill/off = 64 ints)
// ---------------------------------------------------------------------------
__global__ void zero_kernel(int* __restrict__ p){ p[threadIdx.x] = 0; }

// ---------------------------------------------------------------------------
// Tiled fp32 GEMM: C[M,N] = A[M,K] @ W[N,K]^T (+epilogue)
// 64x64 tile, 256 threads, 4x4 per thread, K-major LDS, float4 global loads.
// EPI: 0 = +bias | 1 = plain | 2 = +bias,softplus | 3 = +resid
// ---------------------------------------------------------------------------
template<int EPI>
__global__ __launch_bounds__(256) void gemm_tn(
    const float* __restrict__ A, int lda,
    const float* __restrict__ W, int ldw,
    int M, int N, int K,
    const float* __restrict__ bias,
    const float* __restrict__ resid, int ldr,
    float* __restrict__ out, int ldo)
{
  const int tid = threadIdx.x;
  const int m0 = blockIdx.y * 64;
  const int n0 = blockIdx.x * 64;
  const int tx = tid & 15, ty = tid >> 4;
  const int lr = tid >> 2;          // row handled by this thread in loads
  const int lk = (tid & 3) * 4;     // k base within 16-wide k tile

  __shared__ __align__(16) float As[16][68];
  __shared__ __align__(16) float Ws[16][68];

  float acc[4][4];
  #pragma unroll
  for (int i=0;i<4;i++)
    #pragma unroll
    for (int j=0;j<4;j++) acc[i][j]=0.f;

  const int gm = m0 + lr;
  const int gn = n0 + lr;
  const bool am = (gm < M);
  const bool wn = (gn < N);
  const float* Arow = A + (size_t)gm*lda;
  const float* Wrow = W + (size_t)gn*ldw;

  for (int kt = 0; kt < K; kt += 16){
    float4 a4 = am ? *(const float4*)(Arow + kt + lk) : make_float4(0,0,0,0);
    float4 w4 = wn ? *(const float4*)(Wrow + kt + lk) : make_float4(0,0,0,0);
    As[lk+0][lr]=a4.x; As[lk+1][lr]=a4.y; As[lk+2][lr]=a4.z; As[lk+3][lr]=a4.w;
    Ws[lk+0][lr]=w4.x; Ws[lk+1][lr]=w4.y; Ws[lk+2][lr]=w4.z; Ws[lk+3][lr]=w4.w;
    __syncthreads();
    #pragma unroll
    for (int k=0;k<16;k++){
      float4 av = *(const float4*)&As[k][ty*4];
      float4 bv = *(const float4*)&Ws[k][tx*4];
      float a[4] = {av.x, av.y, av.z, av.w};
      float b[4] = {bv.x, bv.y, bv.z, bv.w};
      #pragma unroll
      for (int i=0;i<4;i++)
        #pragma unroll
        for (int j=0;j<4;j++)
          acc[i][j] = fmaf(a[i], b[j], acc[i][j]);
    }
    __syncthreads();
  }

  #pragma unroll
  for (int i=0;i<4;i++){
    int om = m0 + ty*4 + i;
    if (om >= M) continue;
    #pragma unroll
    for (int j=0;j<4;j++){
      int on = n0 + tx*4 + j;
      if (on >= N) continue;
      float v = acc[i][j];
      if (EPI == 0){ v += bias[on]; }
      else if (EPI == 2){ v += bias[on]; v = (v > 20.f) ? v : log1pf(expf(v)); }
      else if (EPI == 3){ v += resid[(size_t)om*ldr+on]; }
      out[(size_t)om*ldo+on] = v;
    }
  }
}

// ---------------------------------------------------------------------------
// LayerNorm over D=1024, one token per 256-thread block (all fp32)
// ---------------------------------------------------------------------------
__global__ __launch_bounds__(256) void ln_kernel(
    const float* __restrict__ x, const float* __restrict__ g, const float* __restrict__ b,
    float* __restrict__ out)
{
  int tok = blockIdx.x;
  int tid = threadIdx.x;
  const float* row = x + (size_t)tok * DMODEL;
  float v[4];
  float s = 0.f, sq = 0.f;
  #pragma unroll
  for (int j=0;j<4;j++){
    v[j] = row[j*256 + tid];
    s += v[j]; sq += v[j]*v[j];
  }
  #pragma unroll
  for (int o=1;o<64;o<<=1){ s += __shfl_xor(s,o,64); sq += __shfl_xor(sq,o,64); }
  __shared__ float ss[4], ssq[4];
  int wid = tid >> 6, lane = tid & 63;
  if (lane == 0){ ss[wid]=s; ssq[wid]=sq; }
  __syncthreads();
  s  = ss[0]+ss[1]+ss[2]+ss[3];
  sq = ssq[0]+ssq[1]+ssq[2]+ssq[3];
  float mu = s * (1.f/DMODEL);
  float var = sq * (1.f/DMODEL) - mu*mu;
  float rs = rsqrtf(var + 1e-5f);
  #pragma unroll
  for (int j=0;j<4;j++){
    int d = j*256 + tid;
    out[(size_t)tok*DMODEL + d] = (v[j]-mu)*rs*g[d] + b[d];
  }
}

// ---------------------------------------------------------------------------
// Causal depthwise conv (KC=4) + SiLU.  xi = xz[:, 0:2048] (row stride 4096)
// ---------------------------------------------------------------------------
__global__ __launch_bounds__(256) void conv_kernel(
    const float* __restrict__ xz, const float* __restrict__ cw,
    const float* __restrict__ cb, float* __restrict__ xc)
{
  int i = blockIdx.x*256 + threadIdx.x;      // < NTOK*DINNER
  int tok = i >> 11;
  int ch  = i & 2047;
  int t   = tok & (TSEQ-1);
  int b   = tok >> 11;
  float acc = cb[ch];
  #pragma unroll
  for (int k=0;k<4;k++){
    int tt = t + k - 3;
    if (tt >= 0)
      acc = fmaf(cw[ch*4 + k], xz[(size_t)((b<<11)+tt)*4096 + ch], acc);
  }
  xc[i] = siluf(acc);
}

// ---------------------------------------------------------------------------
// Chunked parallel selective scan (3 passes).
// Recurrence h_t = a_t h_{t-1} + b_t, a_t = exp(dt*A):  per chunk of CLEN,
// h_out = P*h_in + Q with P = exp(A*sum dt), Q = scan(h_in=0).
// Pass A: per (b,ch,n,chunk) -> P,Q.   Pass B: serial over 16 chunks -> Hs.
// Pass C: rescan chunk from Hs, y = shfl-reduce(h*C), fuse Dskip + silu(z),
//         write in-place into xc.
// Lane layout (as before): quarter-wave = one channel's 16 states.
// ---------------------------------------------------------------------------
__global__ __launch_bounds__(256) void scan_partial(
    const float* __restrict__ xz, const float* __restrict__ xc,
    const float* __restrict__ proj, const float* __restrict__ A_log,
    float* __restrict__ P, float* __restrict__ Q)
{
  int tid = threadIdx.x;
  int n = tid & 15, chi = tid >> 4;
  int ch = blockIdx.x*16 + chi;
  int c  = blockIdx.y;
  int b  = blockIdx.z;
  float A = -expf(A_log[ch*NSTATE + n]);
  float h = 0.f, sdt = 0.f;
  int tok0 = (b<<11) + c*CLEN;
  for (int i=0;i<CLEN;i++){
    int tok = tok0 + i;
    float dtv = xz[(size_t)tok*4096 + ch];
    float xt  = xc[(size_t)tok*2048 + ch];
    float Bn  = proj[(size_t)tok*96 + 64 + n];
    h = fmaf(expf(dtv*A)*h, 1.f, dtv*xt*Bn);
    h = expf(dtv*A)*h*0.f + h; // (no-op guard removed by compiler)
    sdt += dtv;
  }
  size_t idx = ((((size_t)(b*NCHUNK + c))<<11 | ch)<<4) | n;
  P[idx] = expf(A*sdt);
  Q[idx] = h;
}

__global__ __launch_bounds__(256) void scan_combine(
    const float* __restrict__ P, const float* __restrict__ Q,
    float* __restrict__ Hs)
{
  int g = blockIdx.x*256 + threadIdx.x;   // 65536 = b*32768 + ch*16 + n
  int n = g & 15, ch = (g>>4) & 2047, b = g>>15;
  float hs = 0.f;
  for (int c=0;c<NCHUNK;c++){
    size_t idx = ((((size_t)(b*NCHUNK + c))<<11 | ch)<<4) | n;
    Hs[idx] = hs;
    hs = fmaf(P[idx], hs, Q[idx]);
  }
}

__global__ __launch_bounds__(256) void scan_final(
    const float* __restrict__ xz, float* __restrict__ xc,
    const float* __restrict__ proj, const float* __restrict__ A_log,
    const float* __restrict__ Dskip, const float* __restrict__ Hs)
{
  int tid = threadIdx.x;
  int n = tid & 15, chi = tid >> 4;
  int ch = blockIdx.x*16 + chi;
  int c  = blockIdx.y;
  int b  = blockIdx.z;
  float A  = -expf(A_log[ch*NSTATE + n]);
  float Dv = Dskip[ch];
  size_t idx = ((((size_t)(b*NCHUNK + c))<<11 | ch)<<4) | n;
  float h = Hs[idx];
  int tok0 = (b<<11) + c*CLEN;
  for (int i=0;i<CLEN;i++){
    int tok = tok0 + i;
    float dtv = xz[(size_t)tok*4096 + ch];
    float xt  = xc[(size_t)tok*2048 + ch];
    float Bn  = proj[(size_t)tok*96 + 64 + n];
    float Cn  = proj[(size_t)tok*96 + 80 + n];
    h = expf(dtv*A)*h + dtv*xt*Bn;
    float p = h*Cn;
    p += __shfl_xor(p,1,64);
    p += __shfl_xor(p,2,64);
    p += __shfl_xor(p,4,64);
    p += __shfl_xor(p,8,64);
    if (n == 0){
      float zv = xz[(size_t)tok*4096 + 2048 + ch];
      xc[(size_t)tok*2048 + ch] = (p + xt*Dv) * siluf(zv);
    }
  }
}

// ---------------------------------------------------------------------------
// Router: logits, softmax (-> d_out probs), top-2, atomic expert counts
// ---------------------------------------------------------------------------
__global__ __launch_bounds__(256) void router_kernel(
    const float* __restrict__ hmoe, const float* __restrict__ rw,
    float* __restrict__ probs_out, int* __restrict__ cnt,
    int* __restrict__ tok_e0, int* __restrict__ tok_e1,
    float* __restrict__ tok_w0, float* __restrict__ tok_w1)
{
  int tok = blockIdx.x;
  int tid = threadIdx.x;
  int e = tid >> 5, l = tid & 31;
  float s = 0.f;
  const float* row = hmoe + (size_t)tok*DMODEL;
  const float* wr  = rw + (size_t)e*DMODEL;
  for (int d=l; d<DMODEL; d+=32) s = fmaf(row[d], wr[d], s);
  #pragma unroll
  for (int o=1;o<32;o<<=1) s += __shfl_xor(s,o,64);
  __shared__ float lg[8];
  if (l==0) lg[e]=s;
  __syncthreads();
  if (tid==0){
    float mx = lg[0];
    for (int k=1;k<8;k++) mx = fmaxf(mx, lg[k]);
    float pe[8]; float den=0.f;
    for (int k=0;k<8;k++){ pe[k]=expf(lg[k]-mx); den+=pe[k]; }
    float inv = 1.f/den;
    for (int k=0;k<8;k++) probs_out[tok*8+k] = pe[k]*inv;
    int i0=0;
    for (int k=1;k<8;k++) if (pe[k] > pe[i0]) i0=k;
    int i1 = (i0==0)?1:0;
    for (int k=0;k<8;k++) if (k!=i0 && pe[k] > pe[i1]) i1=k;
    float v0=pe[i0], v1=pe[i1], sw=v0+v1;
    tok_e0[tok]=i0; tok_e1[tok]=i1;
    tok_w0[tok]=v0/sw; tok_w1[tok]=v1/sw;
    atomicAdd(&cnt[i0],1); atomicAdd(&cnt[i1],1);
  }
}

__global__ void prefix_kernel(const int* cnt, int* off, int* fill){
  if (threadIdx.x==0){
    int s=0;
    for (int e=0;e<NEXP;e++){ off[e]=s; s+=cnt[e]; fill[e]=0; }
  }
}

__global__ __launch_bounds__(256) void fill_kernel(
    const int* tok_e0, const int* tok_e1, const float* tok_w0, const float* tok_w1,
    const int* off, int* fill, int* slot_tok, float* slot_w)
{
  int tok = blockIdx.x*256 + threadIdx.x;
  int e0=tok_e0[tok], e1=tok_e1[tok];
  int p0 = atomicAdd(&fill[e0],1); int s0 = off[e0]+p0;
  slot_tok[s0]=tok; slot_w[s0]=tok_w0[tok];
  int p1 = atomicAdd(&fill[e1],1); int s1 = off[e1]+p1;
  slot_tok[s1]=tok; slot_w[s1]=tok_w1[tok];
}

// ---------------------------------------------------------------------------
// MoE expert-gathered GEMM1: H1[slot,DFF] = silu(hmoe[tok] @ w1[e]^T + b1[e])
// ---------------------------------------------------------------------------
__global__ __launch_bounds__(256) void moe_gemm1(
    const float* __restrict__ hmoe, const float* __restrict__ w1, const float* __restrict__ b1,
    const int* __restrict__ cnt, const int* __restrict__ off,
    const int* __restrict__ slot_tok, float* __restrict__ H1)
{
  int e = blockIdx.z;
  int c = cnt[e];
  int r0 = blockIdx.y*64;
  if (r0 >= c) return;
  int base = off[e];
  int tid = threadIdx.x;
  __shared__ int toks[64];
  if (tid < 64) toks[tid] = (r0 + tid < c) ? slot_tok[base + r0 + tid] : -1;
  __syncthreads();

  const float* W = w1 + (size_t)e*DFF*DMODEL;
  int n0 = blockIdx.x*64;
  int tx = tid & 15, ty = tid >> 4;
  int lr = tid >> 2, lk = (tid & 3)*4;
  __shared__ __align__(16) float As[16][68];
  __shared__ __align__(16) float Ws[16][68];
  float acc[4][4];
  #pragma unroll
  for (int i=0;i<4;i++)
    #pragma unroll
    for (int j=0;j<4;j++) acc[i][j]=0.f;

  int tA = toks[lr];
  const float* Arow = hmoe + (size_t)tA*DMODEL;
  const float* Wrow = W + (size_t)(n0+lr)*DMODEL;
  for (int kt=0; kt<DMODEL; kt+=16){
    float4 a4 = (tA>=0) ? *(const float4*)(Arow + kt + lk) : make_float4(0,0,0,0);
    float4 w4 = *(const float4*)(Wrow + kt + lk);
    As[lk+0][lr]=a4.x; As[lk+1][lr]=a4.y; As[lk+2][lr]=a4.z; As[lk+3][lr]=a4.w;
    Ws[lk+0][lr]=w4.x; Ws[lk+1][lr]=w4.y; Ws[lk+2][lr]=w4.z; Ws[lk+3][lr]=w4.w;
    __syncthreads();
    #pragma unroll
    for (int k=0;k<16;k++){
      float4 av = *(const float4*)&As[k][ty*4];
      float4 bv = *(const float4*)&Ws[k][tx*4];
      float a[4] = {av.x, av.y, av.z, av.w};
      float b[4] = {bv.x, bv.y, bv.z, bv.w};
      #pragma unroll
      for (int i=0;i<4;i++)
        #pragma unroll
        for (int j=0;j<4;j++)
          acc[i][j] = fmaf(a[i], b[j], acc[i][j]);
    }
    __syncthreads();
  }
  #pragma unroll
  for (int i=0;i<4;i++){
    int r = ty*4 + i;
    if (toks[r] < 0) continue;
    #pragma unroll
    for (int j=0;j<4;j++){
      int gn = n0 + tx*4 + j;
      float v = acc[i][j] + b1[(size_t)e*DFF + gn];
      H1[(size_t)(base + r0 + r)*DFF + gn] = siluf(v);
    }
  }
}

// ---------------------------------------------------------------------------
// MoE GEMM2: hres[tok] += w_slot * (H1[slot] @ w2[e]^T + b2[e])   (atomic)
// ---------------------------------------------------------------------------
__global__ __launch_bounds__(256) void moe_gemm2(
    const float* __restrict__ H1, const float* __restrict__ w2, const float* __restrict__ b2,
    const int* __restrict__ cnt, const int* __restrict__ off,
    const int* __restrict__ slot_tok, const float* __restrict__ slot_w,
    float* __restrict__ hres)
{
  int e = blockIdx.z;
  int c = cnt[e];
  int r0 = blockIdx.y*64;
  if (r0 >= c) return;
  int base = off[e];
  int tid = threadIdx.x;
  __shared__ int toks[64];
  __shared__ float wts[64];
  if (tid < 64){
    int r = r0 + tid;
    toks[tid] = (r<c) ? slot_tok[base+r] : -1;
    wts[tid]  = (r<c) ? slot_w[base+r] : 0.f;
  }
  __syncthreads();

  const float* W = w2 + (size_t)e*DMODEL*DFF;
  int n0 = blockIdx.x*64;
  int tx = tid & 15, ty = tid >> 4;
  int lr = tid >> 2, lk = (tid & 3)*4;
  bool av_ok = (toks[lr] >= 0);
  __shared__ __align__(16) float As[16][68];
  __shared__ __align__(16) float Ws[16][68];
  float acc[4][4];
  #pragma unroll
  for (int i=0;i<4;i++)
    #pragma unroll
    for (int j=0;j<4;j++) acc[i][j]=0.f;

  const float* Arow = H1 + (size_t)(base + r0 + lr)*DFF;
  const float* Wrow = W + (size_t)(n0+lr)*DFF;
  for (int kt=0; kt<DFF; kt+=16){
    float4 a4 = av_ok ? *(const float4*)(Arow + kt + lk) : make_float4(0,0,0,0);
    float4 w4 = *(const float4*)(Wrow + kt + lk);
    As[lk+0][lr]=a4.x; As[lk+1][lr]=a4.y; As[lk+2][lr]=a4.z; As[lk+3][lr]=a4.w;
    Ws[lk+0][lr]=w4.x; Ws[lk+1][lr]=w4.y; Ws[lk+2][lr]=w4.z; Ws[lk+3][lr]=w4.w;
    __syncthreads();
    #pragma unroll
    for (int k=0;k<16;k++){
      float4 av = *(const float4*)&As[k][ty*4];
      float4 bv = *(const float4*)&Ws[k][tx*4];
      float a[4] = {av.x, av.y, av.z, av.w};
      float b[4] = {bv.x, bv.y, bv.z, bv.w};
      #pragma unroll
      for (int i=0;i<4;i++)
        #pragma unroll
        for (int j=0;j<4;j++)
          acc[i][j] = fmaf(a[i], b[j], acc[i][j]);
    }
    __syncthreads();
  }
  #pragma unroll
  for (int i=0;i<4;i++){
    int t = toks[ty*4+i];
    if (t < 0) continue;
    float w = wts[ty*4+i];
    #pragma unroll
    for (int j=0;j<4;j++){
      int gn = n0 + tx*4 + j;
      float v = acc[i][j] + b2[(size_t)e*DMODEL + gn];
      atomicAdd(&hres[(size_t)t*DMODEL + gn], w*v);
    }
  }
}

__global__ __launch_bounds__(256) void final_kernel(const float* __restrict__ hres,
                                                    float* __restrict__ out)
{
  int i = blockIdx.x*256 + threadIdx.x;
  out[i] = hres[i];
}

// ---------------------------------------------------------------------------
extern "C" void kernel_launch(void* const* d_in, const int* in_sizes, int n_in,
                              void* d_out, int out_size, void* d_ws, size_t ws_size,
                              hipStream_t stream)
{
  const float* x         = (const float*)d_in[0];
  const float* ln_m_g    = (const float*)d_in[1];
  const float* ln_m_b    = (const float*)d_in[2];
  const float* ln_e_g    = (const float*)d_in[3];
  const float* ln_e_b    = (const float*)d_in[4];
  const float* in_proj_w = (const float*)d_in[5];
  const float* in_proj_b = (const float*)d_in[6];
  const float* conv_w    = (const float*)d_in[7];
  const float* conv_b    = (const float*)d_in[8];
  const float* x_proj_w  = (const float*)d_in[9];
  const float* dt_proj_w = (const float*)d_in[10];
  const float* dt_proj_b = (const float*)d_in[11];
  const float* A_log     = (const float*)d_in[12];
  const float* D_skip    = (const float*)d_in[13];
  const float* out_proj_w= (const float*)d_in[14];
  const float* router_w  = (const float*)d_in[15];
  const float* w1        = (const float*)d_in[16];
  const float* b1        = (const float*)d_in[17];
  const float* w2        = (const float*)d_in[18];
  const float* b2        = (const float*)d_in[19];

  // Workspace (all fp32), peak ~97.6 MB with overlays:
  //   [0,64M)       xz [4096,4096]; xi half reused for dt; after scan dead ->
  //                 hres [4096,1024] at [0,16M), H1 [8192,2048] at [16M,80M)
  //   [64M,96M)     xc [4096,2048] -> y in-place -> tail of H1 overlay
  //   [96M,97.5M)   proj [4096,96]
  //   [97.5M,...)   misc (counters + buckets, ~132 KB)
  // d_out[0,16M) doubles as scratch: hn (LN output) before in_proj / after LN2,
  // and P/Q/Hs (3 x 4 MB) during the scan passes (hn is dead there).
  char* ws = (char*)d_ws;
  float* xz   = (float*)(ws + 0);
  float* xc   = (float*)(ws + 67108864ull);
  float* proj = (float*)(ws + 100663296ull);
  char*  misc = ws + 102236160ull;
  float* hres = (float*)(ws + 0);
  float* H1   = (float*)(ws + 16777216ull);
  float* hn   = (float*)d_out;
  float* Pbuf = (float*)d_out;                 // 1M floats
  float* Qbuf = (float*)d_out + (1u<<20);      // 1M floats
  float* Hsb  = (float*)d_out + (2u<<20);      // 1M floats
  int*   cnt      = (int*)(misc);
  int*   fill     = (int*)(misc + 64);
  int*   offp     = (int*)(misc + 128);
  int*   tok_e0   = (int*)(misc + 1024);
  int*   tok_e1   = (int*)(misc + 1024 + 16384);
  float* tok_w0   = (float*)(misc + 1024 + 32768);
  float* tok_w1   = (float*)(misc + 1024 + 49152);
  int*   slot_tok = (int*)(misc + 1024 + 65536);
  float* slot_w   = (float*)(misc + 1024 + 98304);
  float* out_h    = (float*)d_out;
  float* probs_out= (float*)d_out + 4194304;

  zero_kernel<<<1, 64, 0, stream>>>(cnt);

  // ---- Mamba branch ----
  ln_kernel<<<NTOK, 256, 0, stream>>>(x, ln_m_g, ln_m_b, hn);
  gemm_tn<0><<<dim3(64,64), 256, 0, stream>>>(
      hn, DMODEL, in_proj_w, DMODEL, NTOK, 4096, DMODEL,
      in_proj_b, nullptr, 0, xz, 4096);
  conv_kernel<<<NTOK*DINNER/256, 256, 0, stream>>>(xz, conv_w, conv_b, xc);
  gemm_tn<1><<<dim3(2,64), 256, 0, stream>>>(
      xc, DINNER, x_proj_w, DINNER, NTOK, 96, DINNER,
      nullptr, nullptr, 0, proj, 96);
  // dt (softplus) -> dead xi half of xz (ldo = 4096)
  gemm_tn<2><<<dim3(32,64), 256, 0, stream>>>(
      proj, 96, dt_proj_w, DTRANK, NTOK, DINNER, DTRANK,
      dt_proj_b, nullptr, 0, xz, 4096);
  // chunked parallel scan (P/Q/Hs in dead hn region of d_out)
  scan_partial<<<dim3(DINNER/16, NCHUNK, 2), 256, 0, stream>>>(
      xz, xc, proj, A_log, Pbuf, Qbuf);
  scan_combine<<<256, 256, 0, stream>>>(Pbuf, Qbuf, Hsb);
  scan_final<<<dim3(DINNER/16, NCHUNK, 2), 256, 0, stream>>>(
      xz, xc, proj, A_log, D_skip, Hsb);
  // out_proj + residual x -> hres
  gemm_tn<3><<<dim3(16,64), 256, 0, stream>>>(
      xc, DINNER, out_proj_w, DINNER, NTOK, DMODEL, DINNER,
      nullptr, x, DMODEL, hres, DMODEL);

  // ---- MoE branch ----
  ln_kernel<<<NTOK, 256, 0, stream>>>(hres, ln_e_g, ln_e_b, hn);
  router_kernel<<<NTOK, 256, 0, stream>>>(hn, router_w, probs_out, cnt,
                                          tok_e0, tok_e1, tok_w0, tok_w1);
  prefix_kernel<<<1, 64, 0, stream>>>(cnt, offp, fill);
  fill_kernel<<<NTOK/256, 256, 0, stream>>>(tok_e0, tok_e1, tok_w0, tok_w1,
                                            offp, fill, slot_tok, slot_w);
  moe_gemm1<<<dim3(DFF/64, 64, NEXP), 256, 0, stream>>>(
      hn, w1, b1, cnt, offp, slot_tok, H1);
  moe_gemm2<<<dim3(DMODEL/64, 64, NEXP), 256, 0, stream>>>(
      H1, w2, b2, cnt, offp, slot_tok, slot_w, hres);

  final_kernel<<<NTOK*DMODEL/256, 256, 0, stream>>>(hres, out_h);
}

// Round 6
// 1846.249 us; speedup vs baseline: 2.1135x; 1.4094x over previous
//
#include <hip/hip_runtime.h>
#include <hip/hip_bf16.h>
#include <math.h>

#define NTOK   4096   // B*T
#define TSEQ   2048
#define DMODEL 1024
#define DINNER 2048
#define NSTATE 16
#define DTRANK 64
#define NEXP   8
#define DFF    2048
#define NCHUNK 16
#define CLEN   128    // TSEQ / NCHUNK

typedef __attribute__((ext_vector_type(8))) short short8;
typedef __attribute__((ext_vector_type(4))) float f32x4;

__device__ __forceinline__ float siluf(float x){ return x / (1.f + expf(-x)); }

// fp32 -> bf16 (round-to-nearest-even), as raw ushort
__device__ __forceinline__ unsigned short f2bf(float x){
  unsigned int u = __float_as_uint(x);
  unsigned int r = (u + 0x7FFFu + ((u >> 16) & 1u)) >> 16;
  return (unsigned short)r;
}

// ---------------------------------------------------------------------------
// zero counters (cnt/fill/off = 64 ints)
// ---------------------------------------------------------------------------
__global__ void zero_kernel(int* __restrict__ p){ p[threadIdx.x] = 0; }

// ---------------------------------------------------------------------------
// Tiled fp32 GEMM: C[M,N] = A[M,K] @ W[N,K]^T (+epilogue)
// 64x64 tile, 256 threads, 4x4 per thread, K-major LDS, float4 global loads.
// EPI: 0 = +bias | 1 = plain | 2 = +bias,softplus | 3 = +resid
// ---------------------------------------------------------------------------
template<int EPI>
__global__ __launch_bounds__(256) void gemm_tn(
    const float* __restrict__ A, int lda,
    const float* __restrict__ W, int ldw,
    int M, int N, int K,
    const float* __restrict__ bias,
    const float* __restrict__ resid, int ldr,
    float* __restrict__ out, int ldo)
{
  const int tid = threadIdx.x;
  const int m0 = blockIdx.y * 64;
  const int n0 = blockIdx.x * 64;
  const int tx = tid & 15, ty = tid >> 4;
  const int lr = tid >> 2;          // row handled by this thread in loads
  const int lk = (tid & 3) * 4;     // k base within 16-wide k tile

  __shared__ __align__(16) float As[16][68];
  __shared__ __align__(16) float Ws[16][68];

  float acc[4][4];
  #pragma unroll
  for (int i=0;i<4;i++)
    #pragma unroll
    for (int j=0;j<4;j++) acc[i][j]=0.f;

  const int gm = m0 + lr;
  const int gn = n0 + lr;
  const bool am = (gm < M);
  const bool wn = (gn < N);
  const float* Arow = A + (size_t)gm*lda;
  const float* Wrow = W + (size_t)gn*ldw;

  for (int kt = 0; kt < K; kt += 16){
    float4 a4 = am ? *(const float4*)(Arow + kt + lk) : make_float4(0,0,0,0);
    float4 w4 = wn ? *(const float4*)(Wrow + kt + lk) : make_float4(0,0,0,0);
    As[lk+0][lr]=a4.x; As[lk+1][lr]=a4.y; As[lk+2][lr]=a4.z; As[lk+3][lr]=a4.w;
    Ws[lk+0][lr]=w4.x; Ws[lk+1][lr]=w4.y; Ws[lk+2][lr]=w4.z; Ws[lk+3][lr]=w4.w;
    __syncthreads();
    #pragma unroll
    for (int k=0;k<16;k++){
      float4 av = *(const float4*)&As[k][ty*4];
      float4 bv = *(const float4*)&Ws[k][tx*4];
      float a[4] = {av.x, av.y, av.z, av.w};
      float b[4] = {bv.x, bv.y, bv.z, bv.w};
      #pragma unroll
      for (int i=0;i<4;i++)
        #pragma unroll
        for (int j=0;j<4;j++)
          acc[i][j] = fmaf(a[i], b[j], acc[i][j]);
    }
    __syncthreads();
  }

  #pragma unroll
  for (int i=0;i<4;i++){
    int om = m0 + ty*4 + i;
    if (om >= M) continue;
    #pragma unroll
    for (int j=0;j<4;j++){
      int on = n0 + tx*4 + j;
      if (on >= N) continue;
      float v = acc[i][j];
      if (EPI == 0){ v += bias[on]; }
      else if (EPI == 2){ v += bias[on]; v = (v > 20.f) ? v : log1pf(expf(v)); }
      else if (EPI == 3){ v += resid[(size_t)om*ldr+on]; }
      out[(size_t)om*ldo+on] = v;
    }
  }
}

// ---------------------------------------------------------------------------
// LayerNorm over D=1024, one token per 256-thread block (all fp32)
// ---------------------------------------------------------------------------
__global__ __launch_bounds__(256) void ln_kernel(
    const float* __restrict__ x, const float* __restrict__ g, const float* __restrict__ b,
    float* __restrict__ out)
{
  int tok = blockIdx.x;
  int tid = threadIdx.x;
  const float* row = x + (size_t)tok * DMODEL;
  float v[4];
  float s = 0.f, sq = 0.f;
  #pragma unroll
  for (int j=0;j<4;j++){
    v[j] = row[j*256 + tid];
    s += v[j]; sq += v[j]*v[j];
  }
  #pragma unroll
  for (int o=1;o<64;o<<=1){ s += __shfl_xor(s,o,64); sq += __shfl_xor(sq,o,64); }
  __shared__ float ss[4], ssq[4];
  int wid = tid >> 6, lane = tid & 63;
  if (lane == 0){ ss[wid]=s; ssq[wid]=sq; }
  __syncthreads();
  s  = ss[0]+ss[1]+ss[2]+ss[3];
  sq = ssq[0]+ssq[1]+ssq[2]+ssq[3];
  float mu = s * (1.f/DMODEL);
  float var = sq * (1.f/DMODEL) - mu*mu;
  float rs = rsqrtf(var + 1e-5f);
  #pragma unroll
  for (int j=0;j<4;j++){
    int d = j*256 + tid;
    out[(size_t)tok*DMODEL + d] = (v[j]-mu)*rs*g[d] + b[d];
  }
}

// ---------------------------------------------------------------------------
// Causal depthwise conv (KC=4) + SiLU.  xi = xz[:, 0:2048] (row stride 4096)
// ---------------------------------------------------------------------------
__global__ __launch_bounds__(256) void conv_kernel(
    const float* __restrict__ xz, const float* __restrict__ cw,
    const float* __restrict__ cb, float* __restrict__ xc)
{
  int i = blockIdx.x*256 + threadIdx.x;      // < NTOK*DINNER
  int tok = i >> 11;
  int ch  = i & 2047;
  int t   = tok & (TSEQ-1);
  int b   = tok >> 11;
  float acc = cb[ch];
  #pragma unroll
  for (int k=0;k<4;k++){
    int tt = t + k - 3;
    if (tt >= 0)
      acc = fmaf(cw[ch*4 + k], xz[(size_t)((b<<11)+tt)*4096 + ch], acc);
  }
  xc[i] = siluf(acc);
}

// ---------------------------------------------------------------------------
// Chunked parallel selective scan (3 passes), as in round 4 (verified).
// ---------------------------------------------------------------------------
__global__ __launch_bounds__(256) void scan_partial(
    const float* __restrict__ xz, const float* __restrict__ xc,
    const float* __restrict__ proj, const float* __restrict__ A_log,
    float* __restrict__ P, float* __restrict__ Q)
{
  int tid = threadIdx.x;
  int n = tid & 15, chi = tid >> 4;
  int ch = blockIdx.x*16 + chi;
  int c  = blockIdx.y;
  int b  = blockIdx.z;
  float A = -expf(A_log[ch*NSTATE + n]);
  float h = 0.f, sdt = 0.f;
  int tok0 = (b<<11) + c*CLEN;
  for (int i=0;i<CLEN;i++){
    int tok = tok0 + i;
    float dtv = xz[(size_t)tok*4096 + ch];
    float xt  = xc[(size_t)tok*2048 + ch];
    float Bn  = proj[(size_t)tok*96 + 64 + n];
    h = expf(dtv*A)*h + dtv*xt*Bn;
    sdt += dtv;
  }
  size_t idx = ((((size_t)(b*NCHUNK + c))<<11 | ch)<<4) | n;
  P[idx] = expf(A*sdt);
  Q[idx] = h;
}

__global__ __launch_bounds__(256) void scan_combine(
    const float* __restrict__ P, const float* __restrict__ Q,
    float* __restrict__ Hs)
{
  int g = blockIdx.x*256 + threadIdx.x;   // 65536 = b*32768 + ch*16 + n
  int n = g & 15, ch = (g>>4) & 2047, b = g>>15;
  float hs = 0.f;
  for (int c=0;c<NCHUNK;c++){
    size_t idx = ((((size_t)(b*NCHUNK + c))<<11 | ch)<<4) | n;
    Hs[idx] = hs;
    hs = fmaf(P[idx], hs, Q[idx]);
  }
}

__global__ __launch_bounds__(256) void scan_final(
    const float* __restrict__ xz, float* __restrict__ xc,
    const float* __restrict__ proj, const float* __restrict__ A_log,
    const float* __restrict__ Dskip, const float* __restrict__ Hs)
{
  int tid = threadIdx.x;
  int n = tid & 15, chi = tid >> 4;
  int ch = blockIdx.x*16 + chi;
  int c  = blockIdx.y;
  int b  = blockIdx.z;
  float A  = -expf(A_log[ch*NSTATE + n]);
  float Dv = Dskip[ch];
  size_t idx = ((((size_t)(b*NCHUNK + c))<<11 | ch)<<4) | n;
  float h = Hs[idx];
  int tok0 = (b<<11) + c*CLEN;
  for (int i=0;i<CLEN;i++){
    int tok = tok0 + i;
    float dtv = xz[(size_t)tok*4096 + ch];
    float xt  = xc[(size_t)tok*2048 + ch];
    float Bn  = proj[(size_t)tok*96 + 64 + n];
    float Cn  = proj[(size_t)tok*96 + 80 + n];
    h = expf(dtv*A)*h + dtv*xt*Bn;
    float p = h*Cn;
    p += __shfl_xor(p,1,64);
    p += __shfl_xor(p,2,64);
    p += __shfl_xor(p,4,64);
    p += __shfl_xor(p,8,64);
    if (n == 0){
      float zv = xz[(size_t)tok*4096 + 2048 + ch];
      xc[(size_t)tok*2048 + ch] = (p + xt*Dv) * siluf(zv);
    }
  }
}

// ---------------------------------------------------------------------------
// Router: logits, softmax (-> d_out probs), top-2, atomic expert counts
// ---------------------------------------------------------------------------
__global__ __launch_bounds__(256) void router_kernel(
    const float* __restrict__ hmoe, const float* __restrict__ rw,
    float* __restrict__ probs_out, int* __restrict__ cnt,
    int* __restrict__ tok_e0, int* __restrict__ tok_e1,
    float* __restrict__ tok_w0, float* __restrict__ tok_w1)
{
  int tok = blockIdx.x;
  int tid = threadIdx.x;
  int e = tid >> 5, l = tid & 31;
  float s = 0.f;
  const float* row = hmoe + (size_t)tok*DMODEL;
  const float* wr  = rw + (size_t)e*DMODEL;
  for (int d=l; d<DMODEL; d+=32) s = fmaf(row[d], wr[d], s);
  #pragma unroll
  for (int o=1;o<32;o<<=1) s += __shfl_xor(s,o,64);
  __shared__ float lg[8];
  if (l==0) lg[e]=s;
  __syncthreads();
  if (tid==0){
    float mx = lg[0];
    for (int k=1;k<8;k++) mx = fmaxf(mx, lg[k]);
    float pe[8]; float den=0.f;
    for (int k=0;k<8;k++){ pe[k]=expf(lg[k]-mx); den+=pe[k]; }
    float inv = 1.f/den;
    for (int k=0;k<8;k++) probs_out[tok*8+k] = pe[k]*inv;
    int i0=0;
    for (int k=1;k<8;k++) if (pe[k] > pe[i0]) i0=k;
    int i1 = (i0==0)?1:0;
    for (int k=0;k<8;k++) if (k!=i0 && pe[k] > pe[i1]) i1=k;
    float v0=pe[i0], v1=pe[i1], sw=v0+v1;
    tok_e0[tok]=i0; tok_e1[tok]=i1;
    tok_w0[tok]=v0/sw; tok_w1[tok]=v1/sw;
    atomicAdd(&cnt[i0],1); atomicAdd(&cnt[i1],1);
  }
}

__global__ void prefix_kernel(const int* cnt, int* off, int* fill){
  if (threadIdx.x==0){
    int s=0;
    for (int e=0;e<NEXP;e++){ off[e]=s; s+=cnt[e]; fill[e]=0; }
  }
}

__global__ __launch_bounds__(256) void fill_kernel(
    const int* tok_e0, const int* tok_e1, const float* tok_w0, const float* tok_w1,
    const int* off, int* fill, int* slot_tok, float* slot_w)
{
  int tok = blockIdx.x*256 + threadIdx.x;
  int e0=tok_e0[tok], e1=tok_e1[tok];
  int p0 = atomicAdd(&fill[e0],1); int s0 = off[e0]+p0;
  slot_tok[s0]=tok; slot_w[s0]=tok_w0[tok];
  int p1 = atomicAdd(&fill[e1],1); int s1 = off[e1]+p1;
  slot_tok[s1]=tok; slot_w[s1]=tok_w1[tok];
}

// ---------------------------------------------------------------------------
// MoE GEMM1 via bf16 MFMA: H1[slot,DFF] = silu(hmoe[tok] @ w1[e]^T + b1[e])
// 64x64 tile, 4 waves; wave w = rows [16w,16w+16) x 4 col-tiles.
// mfma_f32_16x16x32_bf16: A[m=lane&15][k=quad*8+j]; D: col=lane&15,row=quad*4+reg.
// LDS tiles [row][k], stride 40 shorts (80B: 16B-aligned b128, <=2-way banks).
// ---------------------------------------------------------------------------
__global__ __launch_bounds__(256) void moe_gemm1(
    const float* __restrict__ hmoe, const float* __restrict__ w1, const float* __restrict__ b1,
    const int* __restrict__ cnt, const int* __restrict__ off,
    const int* __restrict__ slot_tok, unsigned short* __restrict__ H1)
{
  int e = blockIdx.z;
  int c = cnt[e];
  int r0 = blockIdx.y*64;
  if (r0 >= c) return;
  int base = off[e];
  int tid = threadIdx.x;
  __shared__ int toks[64];
  if (tid < 64) toks[tid] = (r0 + tid < c) ? slot_tok[base + r0 + tid] : -1;
  __shared__ __align__(16) unsigned short As[64*40];
  __shared__ __align__(16) unsigned short Ws[64*40];
  __syncthreads();

  const int n0   = blockIdx.x*64;
  const int arow = tid >> 2;          // 0..63 staged row
  const int kq   = (tid & 3) * 8;     // k sub-offset 0/8/16/24
  const int tok  = toks[arow];
  const float* Ap = hmoe + (size_t)(tok < 0 ? 0 : tok)*DMODEL + kq;
  const bool aok  = (tok >= 0);
  const float* Wp = w1 + (size_t)e*DFF*DMODEL + (size_t)(n0+arow)*DMODEL + kq;

  const int lane = tid & 63;
  const int wv   = tid >> 6;
  const int qd   = lane >> 4;
  const int mr   = lane & 15;

  f32x4 acc0={0,0,0,0}, acc1={0,0,0,0}, acc2={0,0,0,0}, acc3={0,0,0,0};

  unsigned short* aw = &As[arow*40 + kq];
  unsigned short* ww = &Ws[arow*40 + kq];
  const unsigned short* ard = &As[(wv*16 + mr)*40 + qd*8];
  const unsigned short* brd = &Ws[mr*40 + qd*8];

  for (int kt = 0; kt < DMODEL; kt += 32){
    float4 a0 = aok ? *(const float4*)(Ap + kt)     : make_float4(0,0,0,0);
    float4 a1 = aok ? *(const float4*)(Ap + kt + 4) : make_float4(0,0,0,0);
    float4 w0 = *(const float4*)(Wp + kt);
    float4 w1v= *(const float4*)(Wp + kt + 4);
    short8 av, wvv;
    av[0]=(short)f2bf(a0.x); av[1]=(short)f2bf(a0.y); av[2]=(short)f2bf(a0.z); av[3]=(short)f2bf(a0.w);
    av[4]=(short)f2bf(a1.x); av[5]=(short)f2bf(a1.y); av[6]=(short)f2bf(a1.z); av[7]=(short)f2bf(a1.w);
    wvv[0]=(short)f2bf(w0.x); wvv[1]=(short)f2bf(w0.y); wvv[2]=(short)f2bf(w0.z); wvv[3]=(short)f2bf(w0.w);
    wvv[4]=(short)f2bf(w1v.x); wvv[5]=(short)f2bf(w1v.y); wvv[6]=(short)f2bf(w1v.z); wvv[7]=(short)f2bf(w1v.w);
    __syncthreads();
    *(short8*)aw = av;
    *(short8*)ww = wvv;
    __syncthreads();
    short8 af = *(const short8*)ard;
    short8 b0 = *(const short8*)(brd);
    short8 b1f= *(const short8*)(brd + 16*40);
    short8 b2f= *(const short8*)(brd + 32*40);
    short8 b3f= *(const short8*)(brd + 48*40);
    acc0 = __builtin_amdgcn_mfma_f32_16x16x32_bf16(af, b0, acc0, 0,0,0);
    acc1 = __builtin_amdgcn_mfma_f32_16x16x32_bf16(af, b1f, acc1, 0,0,0);
    acc2 = __builtin_amdgcn_mfma_f32_16x16x32_bf16(af, b2f, acc2, 0,0,0);
    acc3 = __builtin_amdgcn_mfma_f32_16x16x32_bf16(af, b3f, acc3, 0,0,0);
  }

  #pragma unroll
  for (int ct=0; ct<4; ct++){
    f32x4 a = (ct==0)?acc0:(ct==1)?acc1:(ct==2)?acc2:acc3;
    int colg = n0 + ct*16 + mr;
    float bias = b1[(size_t)e*DFF + colg];
    #pragma unroll
    for (int r=0;r<4;r++){
      int sl = wv*16 + qd*4 + r;
      if (toks[sl] < 0) continue;
      float v = a[r] + bias;
      H1[(size_t)(base + r0 + sl)*DFF + colg] = f2bf(siluf(v));
    }
  }
}

// ---------------------------------------------------------------------------
// MoE GEMM2 via bf16 MFMA: hres[tok] += w_slot*(H1[slot] @ w2[e]^T + b2[e])
// ---------------------------------------------------------------------------
__global__ __launch_bounds__(256) void moe_gemm2(
    const unsigned short* __restrict__ H1, const float* __restrict__ w2,
    const float* __restrict__ b2,
    const int* __restrict__ cnt, const int* __restrict__ off,
    const int* __restrict__ slot_tok, const float* __restrict__ slot_w,
    float* __restrict__ hres)
{
  int e = blockIdx.z;
  int c = cnt[e];
  int r0 = blockIdx.y*64;
  if (r0 >= c) return;
  int base = off[e];
  int tid = threadIdx.x;
  __shared__ int toks[64];
  __shared__ float wts[64];
  if (tid < 64){
    int r = r0 + tid;
    toks[tid] = (r<c) ? slot_tok[base+r] : -1;
    wts[tid]  = (r<c) ? slot_w[base+r] : 0.f;
  }
  __shared__ __align__(16) unsigned short As[64*40];
  __shared__ __align__(16) unsigned short Ws[64*40];
  __syncthreads();

  const int n0   = blockIdx.x*64;
  const int arow = tid >> 2;
  const int kq   = (tid & 3) * 8;
  const bool aok = (toks[arow] >= 0);
  const unsigned short* Ap = H1 + (size_t)(base + r0 + (aok ? arow : 0))*DFF + kq;
  const float* Wp = w2 + (size_t)e*DMODEL*DFF + (size_t)(n0+arow)*DFF + kq;

  const int lane = tid & 63;
  const int wv   = tid >> 6;
  const int qd   = lane >> 4;
  const int mr   = lane & 15;

  f32x4 acc0={0,0,0,0}, acc1={0,0,0,0}, acc2={0,0,0,0}, acc3={0,0,0,0};

  unsigned short* aw = &As[arow*40 + kq];
  unsigned short* ww = &Ws[arow*40 + kq];
  const unsigned short* ard = &As[(wv*16 + mr)*40 + qd*8];
  const unsigned short* brd = &Ws[mr*40 + qd*8];

  const short8 zero8 = {0,0,0,0,0,0,0,0};
  for (int kt = 0; kt < DFF; kt += 32){
    short8 av = aok ? *(const short8*)(Ap + kt) : zero8;
    float4 w0 = *(const float4*)(Wp + kt);
    float4 w1v= *(const float4*)(Wp + kt + 4);
    short8 wvv;
    wvv[0]=(short)f2bf(w0.x); wvv[1]=(short)f2bf(w0.y); wvv[2]=(short)f2bf(w0.z); wvv[3]=(short)f2bf(w0.w);
    wvv[4]=(short)f2bf(w1v.x); wvv[5]=(short)f2bf(w1v.y); wvv[6]=(short)f2bf(w1v.z); wvv[7]=(short)f2bf(w1v.w);
    __syncthreads();
    *(short8*)aw = av;
    *(short8*)ww = wvv;
    __syncthreads();
    short8 af = *(const short8*)ard;
    short8 b0 = *(const short8*)(brd);
    short8 b1f= *(const short8*)(brd + 16*40);
    short8 b2f= *(const short8*)(brd + 32*40);
    short8 b3f= *(const short8*)(brd + 48*40);
    acc0 = __builtin_amdgcn_mfma_f32_16x16x32_bf16(af, b0, acc0, 0,0,0);
    acc1 = __builtin_amdgcn_mfma_f32_16x16x32_bf16(af, b1f, acc1, 0,0,0);
    acc2 = __builtin_amdgcn_mfma_f32_16x16x32_bf16(af, b2f, acc2, 0,0,0);
    acc3 = __builtin_amdgcn_mfma_f32_16x16x32_bf16(af, b3f, acc3, 0,0,0);
  }

  #pragma unroll
  for (int ct=0; ct<4; ct++){
    f32x4 a = (ct==0)?acc0:(ct==1)?acc1:(ct==2)?acc2:acc3;
    int colg = n0 + ct*16 + mr;
    float bias = b2[(size_t)e*DMODEL + colg];
    #pragma unroll
    for (int r=0;r<4;r++){
      int sl = wv*16 + qd*4 + r;
      int t = toks[sl];
      if (t < 0) continue;
      float v = a[r] + bias;
      atomicAdd(&hres[(size_t)t*DMODEL + colg], wts[sl]*v);
    }
  }
}

__global__ __launch_bounds__(256) void final_kernel(const float* __restrict__ hres,
                                                    float* __restrict__ out)
{
  int i = blockIdx.x*256 + threadIdx.x;
  out[i] = hres[i];
}

// ---------------------------------------------------------------------------
extern "C" void kernel_launch(void* const* d_in, const int* in_sizes, int n_in,
                              void* d_out, int out_size, void* d_ws, size_t ws_size,
                              hipStream_t stream)
{
  const float* x         = (const float*)d_in[0];
  const float* ln_m_g    = (const float*)d_in[1];
  const float* ln_m_b    = (const float*)d_in[2];
  const float* ln_e_g    = (const float*)d_in[3];
  const float* ln_e_b    = (const float*)d_in[4];
  const float* in_proj_w = (const float*)d_in[5];
  const float* in_proj_b = (const float*)d_in[6];
  const float* conv_w    = (const float*)d_in[7];
  const float* conv_b    = (const float*)d_in[8];
  const float* x_proj_w  = (const float*)d_in[9];
  const float* dt_proj_w = (const float*)d_in[10];
  const float* dt_proj_b = (const float*)d_in[11];
  const float* A_log     = (const float*)d_in[12];
  const float* D_skip    = (const float*)d_in[13];
  const float* out_proj_w= (const float*)d_in[14];
  const float* router_w  = (const float*)d_in[15];
  const float* w1        = (const float*)d_in[16];
  const float* b1        = (const float*)d_in[17];
  const float* w2        = (const float*)d_in[18];
  const float* b2        = (const float*)d_in[19];

  // Workspace (fp32 unless noted), peak ~97.6 MB with overlays:
  //   [0,64M)       xz [4096,4096]; xi half reused for dt; after scan dead ->
  //                 hres [4096,1024] at [0,16M), H1 bf16 [8192,2048] at [16M,48M)
  //   [64M,96M)     xc [4096,2048] -> y in-place
  //   [96M,97.5M)   proj [4096,96]
  //   [97.5M,...)   misc (counters + buckets, ~132 KB)
  // d_out[0,16M) doubles as scratch: hn (LN output), P/Q/Hs during scan.
  char* ws = (char*)d_ws;
  float* xz   = (float*)(ws + 0);
  float* xc   = (float*)(ws + 67108864ull);
  float* proj = (float*)(ws + 100663296ull);
  char*  misc = ws + 102236160ull;
  float* hres = (float*)(ws + 0);
  unsigned short* H1 = (unsigned short*)(ws + 16777216ull);
  float* hn   = (float*)d_out;
  float* Pbuf = (float*)d_out;                 // 1M floats
  float* Qbuf = (float*)d_out + (1u<<20);      // 1M floats
  float* Hsb  = (float*)d_out + (2u<<20);      // 1M floats
  int*   cnt      = (int*)(misc);
  int*   fill     = (int*)(misc + 64);
  int*   offp     = (int*)(misc + 128);
  int*   tok_e0   = (int*)(misc + 1024);
  int*   tok_e1   = (int*)(misc + 1024 + 16384);
  float* tok_w0   = (float*)(misc + 1024 + 32768);
  float* tok_w1   = (float*)(misc + 1024 + 49152);
  int*   slot_tok = (int*)(misc + 1024 + 65536);
  float* slot_w   = (float*)(misc + 1024 + 98304);
  float* out_h    = (float*)d_out;
  float* probs_out= (float*)d_out + 4194304;

  zero_kernel<<<1, 64, 0, stream>>>(cnt);

  // ---- Mamba branch ----
  ln_kernel<<<NTOK, 256, 0, stream>>>(x, ln_m_g, ln_m_b, hn);
  gemm_tn<0><<<dim3(64,64), 256, 0, stream>>>(
      hn, DMODEL, in_proj_w, DMODEL, NTOK, 4096, DMODEL,
      in_proj_b, nullptr, 0, xz, 4096);
  conv_kernel<<<NTOK*DINNER/256, 256, 0, stream>>>(xz, conv_w, conv_b, xc);
  gemm_tn<1><<<dim3(2,64), 256, 0, stream>>>(
      xc, DINNER, x_proj_w, DINNER, NTOK, 96, DINNER,
      nullptr, nullptr, 0, proj, 96);
  // dt (softplus) -> dead xi half of xz (ldo = 4096)
  gemm_tn<2><<<dim3(32,64), 256, 0, stream>>>(
      proj, 96, dt_proj_w, DTRANK, NTOK, DINNER, DTRANK,
      dt_proj_b, nullptr, 0, xz, 4096);
  // chunked parallel scan (P/Q/Hs in dead hn region of d_out)
  scan_partial<<<dim3(DINNER/16, NCHUNK, 2), 256, 0, stream>>>(
      xz, xc, proj, A_log, Pbuf, Qbuf);
  scan_combine<<<256, 256, 0, stream>>>(Pbuf, Qbuf, Hsb);
  scan_final<<<dim3(DINNER/16, NCHUNK, 2), 256, 0, stream>>>(
      xz, xc, proj, A_log, D_skip, Hsb);
  // out_proj + residual x -> hres
  gemm_tn<3><<<dim3(16,64), 256, 0, stream>>>(
      xc, DINNER, out_proj_w, DINNER, NTOK, DMODEL, DINNER,
      nullptr, x, DMODEL, hres, DMODEL);

  // ---- MoE branch ----
  ln_kernel<<<NTOK, 256, 0, stream>>>(hres, ln_e_g, ln_e_b, hn);
  router_kernel<<<NTOK, 256, 0, stream>>>(hn, router_w, probs_out, cnt,
                                          tok_e0, tok_e1, tok_w0, tok_w1);
  prefix_kernel<<<1, 64, 0, stream>>>(cnt, offp, fill);
  fill_kernel<<<NTOK/256, 256, 0, stream>>>(tok_e0, tok_e1, tok_w0, tok_w1,
                                            offp, fill, slot_tok, slot_w);
  moe_gemm1<<<dim3(DFF/64, 64, NEXP), 256, 0, stream>>>(
      hn, w1, b1, cnt, offp, slot_tok, H1);
  moe_gemm2<<<dim3(DMODEL/64, 64, NEXP), 256, 0, stream>>>(
      H1, w2, b2, cnt, offp, slot_tok, slot_w, hres);

  final_kernel<<<NTOK*DMODEL/256, 256, 0, stream>>>(hres, out_h);
}